// Round 7
// baseline (215.998 us; speedup 1.0000x reference)
//
#include <hip/hip_runtime.h>
#include <hip/hip_bf16.h>
#include <math.h>

// SS2D (VMamba) forward, MI355X. Constants from the reference.
#define DM 96
#define DI 192
#define NS 16            // state dim N
#define KK 4             // directions
#define RR 6             // dt rank
#define HH 56
#define WW 56
#define LL (HH*WW)       // 3136
#define RN (RR + 2*NS)   // 38 rows of x_dbl
#define NCH 64           // scan chunks per sequence
#define CLL (LL/NCH)     // 49 steps per chunk

__device__ __forceinline__ float silu_f(float x) { return x / (1.f + __expf(-x)); }
__device__ __forceinline__ float softplus_f(float x) {
    return (x > 20.f) ? x : log1pf(__expf(x));
}

// K1: tiled GEMM xz[o][l]; o<DI -> xc_t[o][l]; o>=DI -> silu -> z_nat[l][o-DI]
__global__ __launch_bounds__(256) void k_inproj(
        const float* __restrict__ x, const float* __restrict__ w,
        float* __restrict__ xc_t, float* __restrict__ z_nat) {
    __shared__ float xt[64 * 100];
    __shared__ float wt[32 * 100];
    const int l0 = blockIdx.x * 64;
    const int o0 = blockIdx.y * 32;
    const int tid = threadIdx.x;
    for (int i = tid; i < 64 * 96; i += 256) {
        int r = i / 96, c = i % 96;
        xt[r * 100 + c] = x[(size_t)(l0 + r) * DM + c];
    }
    for (int i = tid; i < 32 * 96; i += 256) {
        int r = i / 96, c = i % 96;
        wt[r * 100 + c] = w[(size_t)(o0 + r) * DM + c];
    }
    __syncthreads();
    const int tx = tid & 15, ty = tid >> 4;        // tx: o, ty: l
    float acc[4][2] = {};
    for (int c = 0; c < 96; c += 4) {
        float4 av[4], bv[2];
#pragma unroll
        for (int i = 0; i < 4; ++i) av[i] = *(const float4*)&xt[(ty + 16 * i) * 100 + c];
#pragma unroll
        for (int j = 0; j < 2; ++j) bv[j] = *(const float4*)&wt[(tx + 16 * j) * 100 + c];
#pragma unroll
        for (int i = 0; i < 4; ++i)
#pragma unroll
            for (int j = 0; j < 2; ++j) {
                acc[i][j] = fmaf(av[i].x, bv[j].x, acc[i][j]);
                acc[i][j] = fmaf(av[i].y, bv[j].y, acc[i][j]);
                acc[i][j] = fmaf(av[i].z, bv[j].z, acc[i][j]);
                acc[i][j] = fmaf(av[i].w, bv[j].w, acc[i][j]);
            }
    }
    __syncthreads();
    float* ot = xt;                                // reuse as [o][l] 32x65
#pragma unroll
    for (int j = 0; j < 2; ++j)
#pragma unroll
        for (int i = 0; i < 4; ++i)
            ot[(tx + 16 * j) * 65 + (ty + 16 * i)] = acc[i][j];
    __syncthreads();
    if (o0 < DI) {
        for (int i = tid; i < 32 * 64; i += 256) {
            int ol = i >> 6, ll = i & 63;
            xc_t[(size_t)(o0 + ol) * LL + l0 + ll] = ot[ol * 65 + ll];
        }
    } else {
        for (int i = tid; i < 32 * 64; i += 256) {
            int ll = i >> 5, ol = i & 31;
            z_nat[(size_t)(l0 + ll) * DI + (o0 - DI) + ol] = silu_f(ot[ol * 65 + ll]);
        }
    }
}

// K2: depthwise 3x3 conv SAME + bias + silu + spatial transpose, band-split.
__global__ __launch_bounds__(256) void k_convT(
        const float* __restrict__ xc_t, const float* __restrict__ cw,
        const float* __restrict__ cb, float* __restrict__ xconv, float* __restrict__ xs1) {
    __shared__ float in_s[16 * 56];
    __shared__ float out_s[14 * 57];
    const int d = blockIdx.x;
    const int h0 = blockIdx.y * 14;
    const int tid = threadIdx.x;
    const float* in = xc_t + (size_t)d * LL;
    for (int i = tid; i < 16 * 56; i += 256) {
        int r = i / 56 - 1 + h0;
        int cpos = i % 56;
        in_s[i] = (r >= 0 && r < HH) ? in[r * WW + cpos] : 0.f;
    }
    __syncthreads();
    const float b0 = cb[d];
    float w9[9];
#pragma unroll
    for (int i = 0; i < 9; ++i) w9[i] = cw[d * 9 + i];
    for (int i = tid; i < 14 * 56; i += 256) {
        int hh = i / 56, w = i % 56;
        float acc = b0;
#pragma unroll
        for (int di = 0; di < 3; ++di)
#pragma unroll
            for (int dj = 0; dj < 3; ++dj) {
                int w2 = w + dj - 1;
                if (w2 < 0 || w2 >= WW) continue;
                acc = fmaf(in_s[(hh + di) * 56 + w2], w9[di * 3 + dj], acc);
            }
        acc = silu_f(acc);
        xconv[(size_t)d * LL + (h0 + hh) * WW + w] = acc;
        out_s[hh * 57 + w] = acc;
    }
    __syncthreads();
    for (int i = tid; i < 14 * 56; i += 256) {
        int w = i / 14, hh = i % 14;
        xs1[(size_t)d * LL + w * HH + h0 + hh] = out_s[hh * 57 + w];
    }
}

// K3: x_dbl + delta fused, l-tile 32. Both operands LDS-staged. Grid (98, 4).
__global__ __launch_bounds__(256) void k_xdblD(
        const float* __restrict__ xconv, const float* __restrict__ xs1,
        const float* __restrict__ pw, const float* __restrict__ dtw,
        const float* __restrict__ dtb,
        float* __restrict__ Bn, float* __restrict__ Cn, float* __restrict__ delta) {
    __shared__ float xt[DI * 32];                  // [d][sx]
    __shared__ float wk_s[32 * DI];                // [col][d]
    __shared__ float dtS[RR * 33];
    const int k = blockIdx.y;
    const int l0 = blockIdx.x * 32;
    const int tid = threadIdx.x;
    const float* in = (k & 1) ? xs1 : xconv;
    const float* wk = pw + (size_t)k * RN * DI;
    for (int i = tid; i < DI * 32; i += 256) {
        int d = i >> 5, lx = i & 31;
        xt[i] = in[(size_t)d * LL + l0 + lx];
    }
    {
        const float4* src = (const float4*)(wk + RR * DI);
        float4* dst = (float4*)wk_s;
        for (int i = tid; i < (32 * DI) / 4; i += 256) dst[i] = src[i];
    }
    __syncthreads();
    if (tid < RR * 32) {
        int r = tid >> 5, lx = tid & 31;
        const float* wr = wk + r * DI;
        float acc = 0.f;
#pragma unroll 8
        for (int d = 0; d < DI; ++d) acc = fmaf(xt[(d << 5) + lx], wr[d], acc);
        dtS[r * 33 + lx] = acc;
    }
    {
        const int sx = tid & 31, cg = tid >> 5;
        float acc4[4] = {};
        for (int d = 0; d < DI; d += 4) {
            float x0 = xt[(d + 0) * 32 + sx];
            float x1 = xt[(d + 1) * 32 + sx];
            float x2 = xt[(d + 2) * 32 + sx];
            float x3 = xt[(d + 3) * 32 + sx];
#pragma unroll
            for (int j = 0; j < 4; ++j) {
                float4 wv = *(const float4*)&wk_s[(cg + 8 * j) * DI + d];
                acc4[j] = fmaf(x0, wv.x, acc4[j]);
                acc4[j] = fmaf(x1, wv.y, acc4[j]);
                acc4[j] = fmaf(x2, wv.z, acc4[j]);
                acc4[j] = fmaf(x3, wv.w, acc4[j]);
            }
        }
        int s = l0 + sx;
#pragma unroll
        for (int j = 0; j < 4; ++j) {
            int col = cg + 8 * j;
            if (col < NS) Bn[((size_t)k * LL + s) * NS + col] = acc4[j];
            else          Cn[((size_t)k * LL + s) * NS + (col - NS)] = acc4[j];
        }
    }
    __syncthreads();
    for (int oi = tid; oi < DI * 32; oi += 256) {
        int d = oi >> 5, sl = oi & 31;
        int kd = k * DI + d;
        const float* wr = dtw + (size_t)kd * RR;
        float acc = dtb[kd];
#pragma unroll
        for (int r = 0; r < RR; ++r) acc = fmaf(dtS[r * 33 + sl], wr[r], acc);
        delta[(size_t)kd * LL + l0 + sl] = softplus_f(acc);
    }
}

// K4: chunked selective scan, software-pipelined (2-deep, groups of 4).
// Direct coalesced stores to ybuf[kd][im] (im = position in the direction's own
// spatial frame; contiguous 16-runs per quarter-wave -> coalesced).
__global__ __launch_bounds__(1024, 8) void k_scan(
        const float* __restrict__ delta, const float* __restrict__ Bn,
        const float* __restrict__ Cn,
        const float* __restrict__ xconv, const float* __restrict__ xs1,
        const float* __restrict__ A_logs, const float* __restrict__ Ds,
        float* __restrict__ ybuf) {
    __shared__ float sP[NCH * NS];
    __shared__ float sH[NCH * NS];
    int b = blockIdx.x;
    int k = b / DI, d = b % DI;
    int tid = threadIdx.x;
    int c = tid >> 4, n = tid & 15;
    int kd = k * DI + d;
    float An = -__expf(A_logs[kd * NS + n]);
    float Dv = Ds[kd];
    const float* del = delta + (size_t)kd * LL;
    const float* uP  = ((k & 1) ? xs1 : xconv) + (size_t)d * LL;
    const float* Bb  = Bn + (size_t)k * LL * NS;
    const float* Cb  = Cn + (size_t)k * LL * NS;
    const bool fwd = (k < 2);
    const int t0 = c * CLL;
    const int im0 = fwd ? t0 : (LL - 1 - t0);
    const int stp = fwd ? 1 : -1;
    const int stpN = stp * NS;

    const float* pd = del + im0;
    const float* pu = uP + im0;
    const float* pB = Bb + (size_t)im0 * NS + n;
    const float* pC = Cb + (size_t)im0 * NS + n;

    // ---- Phase 1: chunk-local scan, pipelined over 12 groups of 4 + 1 tail ----
    float P = 1.f, h = 0.f;
    {
        float ca[4], cu[4], cb4[4], na[4], nu[4], nb4[4];
#define LD1(A_, U_, B_, base) do { int _o = (base); \
        _Pragma("unroll") for (int j = 0; j < 4; ++j) { \
            A_[j] = pd[stp * (_o + j)]; U_[j] = pu[stp * (_o + j)]; \
            B_[j] = pB[stpN * (_o + j)]; } } while (0)
#define CP1(A_, U_, B_) do { \
        _Pragma("unroll") for (int j = 0; j < 4; ++j) { \
            float dA = __expf(A_[j] * An); \
            h = fmaf(dA, h, A_[j] * B_[j] * U_[j]); P *= dA; } } while (0)
        LD1(ca, cu, cb4, 0);
        for (int g = 0; g < 12; g += 2) {
            LD1(na, nu, nb4, (g + 1) * 4);
            CP1(ca, cu, cb4);
            if (g + 2 < 12) LD1(ca, cu, cb4, (g + 2) * 4);
            CP1(na, nu, nb4);
        }
        {   // tail tl = 48
            float dl = pd[stp * 48], u = pu[stp * 48], Bv = pB[stpN * 48];
            float dA = __expf(dl * An);
            h = fmaf(dA, h, dl * Bv * u);
            P *= dA;
        }
#undef LD1
#undef CP1
    }
    sP[c * NS + n] = P;
    sH[c * NS + n] = h;
    __syncthreads();
    float hin = 0.f;
    for (int cc = 0; cc < c; ++cc)
        hin = fmaf(sP[cc * NS + n], hin, sH[cc * NS + n]);

    // ---- Phase 2: rescan with carry, pipelined; emit y ----
    float h2 = hin;
    float yreg[4] = {0.f, 0.f, 0.f, 0.f};
    {
        float ca[4], cu[4], cb4[4], cc4[4], na[4], nu[4], nb4[4], nc4[4];
#define LD2(A_, U_, B_, C_, base) do { int _o = (base); \
        _Pragma("unroll") for (int j = 0; j < 4; ++j) { \
            A_[j] = pd[stp * (_o + j)]; U_[j] = pu[stp * (_o + j)]; \
            B_[j] = pB[stpN * (_o + j)]; C_[j] = pC[stpN * (_o + j)]; } } while (0)
#define CP2(A_, U_, B_, C_, base) do { int _o = (base); \
        _Pragma("unroll") for (int j = 0; j < 4; ++j) { \
            float dA = __expf(A_[j] * An); \
            h2 = fmaf(dA, h2, A_[j] * B_[j] * U_[j]); \
            float acc = h2 * C_[j]; \
            acc += __shfl_xor(acc, 8, 64); \
            acc += __shfl_xor(acc, 4, 64); \
            acc += __shfl_xor(acc, 2, 64); \
            acc += __shfl_xor(acc, 1, 64); \
            acc = fmaf(Dv, U_[j], acc); \
            int tl = _o + j; \
            if ((tl & 15) == n) yreg[tl >> 4] = acc; } } while (0)
        LD2(ca, cu, cb4, cc4, 0);
        for (int g = 0; g < 12; g += 2) {
            LD2(na, nu, nb4, nc4, (g + 1) * 4);
            CP2(ca, cu, cb4, cc4, g * 4);
            if (g + 2 < 12) LD2(ca, cu, cb4, cc4, (g + 2) * 4);
            CP2(na, nu, nb4, nc4, (g + 1) * 4);
        }
        {   // tail tl = 48
            float dl = pd[stp * 48], u = pu[stp * 48];
            float Bv = pB[stpN * 48], Cv = pC[stpN * 48];
            float dA = __expf(dl * An);
            h2 = fmaf(dA, h2, dl * Bv * u);
            float acc = h2 * Cv;
            acc += __shfl_xor(acc, 8, 64);
            acc += __shfl_xor(acc, 4, 64);
            acc += __shfl_xor(acc, 2, 64);
            acc += __shfl_xor(acc, 1, 64);
            acc = fmaf(Dv, u, acc);
            if (n == 0) yreg[3] = acc;
        }
#undef LD2
#undef CP2
    }
    // direct coalesced stores (R4 scheme): ybuf[kd][im], im in own spatial frame
    float* yo = ybuf + (size_t)kd * LL;
#pragma unroll
    for (int j = 0; j < 3; ++j) {
        int t = t0 + j * 16 + n;
        yo[fwd ? t : (LL - 1 - t)] = yreg[j];
    }
    if (n == 0) {
        int t = t0 + 48;
        yo[fwd ? t : (LL - 1 - t)] = yreg[3];
    }
}

// K5: merge 4 directions -> ym[d][p] (natural space). One block per channel d.
// k=0,2 rows are already natural; k=1,3 rows are transposed-space: LDS 56x57 tile.
__global__ __launch_bounds__(256) void k_merge4(
        const float* __restrict__ ybuf, float* __restrict__ ym) {
    __shared__ float ts[HH * 57];
    const int d = blockIdx.x;
    const int tid = threadIdx.x;
    const float* r1 = ybuf + (size_t)(DI + d) * LL;
    const float* r3 = ybuf + (size_t)(3 * DI + d) * LL;
    // load transposed-space rows, store into tile at natural (h,w): s = w*56+h
    for (int s = tid; s < LL; s += 256) {
        int w = s / HH, h = s % HH;
        ts[h * 57 + w] = r1[s] + r3[s];
    }
    __syncthreads();
    const float* r0 = ybuf + (size_t)d * LL;
    const float* r2 = ybuf + (size_t)(2 * DI + d) * LL;
    float* yo = ym + (size_t)d * LL;
    for (int p = tid; p < LL; p += 256) {
        int h = p / WW, w = p % WW;
        yo[p] = r0[p] + r2[p] + ts[h * 57 + w];
    }
}

// K6: LayerNorm + gate(z) + out-proj. 32 l per block, grid 98.
__global__ __launch_bounds__(256) void k_lnout(
        const float* __restrict__ ym, const float* __restrict__ z_nat,
        const float* __restrict__ lnw, const float* __restrict__ lnb,
        const float* __restrict__ ow, float* __restrict__ out) {
    __shared__ float yv[32 * 196];
    __shared__ float ow_s[48 * 196];
    __shared__ float mean_s[32], inv_s[32];
    const int l0 = blockIdx.x * 32;
    const int tid = threadIdx.x;
    // load merged y: coalesced 128B runs over p for each d
    for (int i = tid; i < DI * 32; i += 256) {
        int d = i >> 5, p = i & 31;
        yv[p * 196 + d] = ym[(size_t)d * LL + l0 + p];
    }
    __syncthreads();
    // LN stats: 8 lanes per p
    {
        int p = tid >> 3, e = tid & 7;
        float s1 = 0.f;
#pragma unroll
        for (int m = 0; m < 24; ++m) s1 += yv[p * 196 + e + 8 * m];
        s1 += __shfl_xor(s1, 4, 64);
        s1 += __shfl_xor(s1, 2, 64);
        s1 += __shfl_xor(s1, 1, 64);
        float mean = s1 * (1.f / DI);
        float s2 = 0.f;
#pragma unroll
        for (int m = 0; m < 24; ++m) {
            float dv = yv[p * 196 + e + 8 * m] - mean;
            s2 = fmaf(dv, dv, s2);
        }
        s2 += __shfl_xor(s2, 4, 64);
        s2 += __shfl_xor(s2, 2, 64);
        s2 += __shfl_xor(s2, 1, 64);
        if (e == 0) {
            mean_s[p] = mean;
            inv_s[p] = rsqrtf(s2 * (1.f / DI) + 1e-5f);
        }
    }
    __syncthreads();
    // normalize + gate (d-fast mapping: coalesced z reads)
    for (int i = tid; i < DI * 32; i += 256) {
        int p = i / DI, d = i % DI;
        float yn = (yv[p * 196 + d] - mean_s[p]) * inv_s[p] * lnw[d] + lnb[d];
        yv[p * 196 + d] = yn * z_nat[(size_t)(l0 + p) * DI + d];
    }
    __syncthreads();
    // out-proj: two passes of 48 o-rows
    const int ty = tid >> 4, tx = tid & 15;        // ty: l-pair, tx: o
#pragma unroll
    for (int pass = 0; pass < 2; ++pass) {
        for (int i = tid; i < 48 * DI; i += 256) {
            int o = i / DI, dd = i % DI;
            ow_s[o * 196 + dd] = ow[(size_t)(pass * 48 + o) * DI + dd];
        }
        __syncthreads();
        float acc[2][3] = {};
        for (int dd = 0; dd < DI; dd += 4) {
            float4 a0 = *(const float4*)&yv[(ty * 2 + 0) * 196 + dd];
            float4 a1 = *(const float4*)&yv[(ty * 2 + 1) * 196 + dd];
#pragma unroll
            for (int j = 0; j < 3; ++j) {
                float4 bv = *(const float4*)&ow_s[(tx + 16 * j) * 196 + dd];
                acc[0][j] += a0.x * bv.x + a0.y * bv.y + a0.z * bv.z + a0.w * bv.w;
                acc[1][j] += a1.x * bv.x + a1.y * bv.y + a1.z * bv.z + a1.w * bv.w;
            }
        }
#pragma unroll
        for (int il = 0; il < 2; ++il)
#pragma unroll
            for (int j = 0; j < 3; ++j)
                out[(size_t)(l0 + ty * 2 + il) * DM + pass * 48 + tx + 16 * j] = acc[il][j];
        __syncthreads();
    }
}

extern "C" void kernel_launch(void* const* d_in, const int* in_sizes, int n_in,
                              void* d_out, int out_size, void* d_ws, size_t ws_size,
                              hipStream_t stream) {
    const float* x    = (const float*)d_in[0];
    const float* ipw  = (const float*)d_in[1];
    const float* cw   = (const float*)d_in[2];
    const float* cb   = (const float*)d_in[3];
    const float* xpw  = (const float*)d_in[4];
    const float* dtw  = (const float*)d_in[5];
    const float* dtb  = (const float*)d_in[6];
    const float* alog = (const float*)d_in[7];
    const float* Dsp  = (const float*)d_in[8];
    const float* lnw  = (const float*)d_in[9];
    const float* lnb  = (const float*)d_in[10];
    const float* ow   = (const float*)d_in[11];
    float* out = (float*)d_out;

    float* ws     = (float*)d_ws;
    float* xc_t   = ws;                             // DI*LL (dead after convT)
    float* z_nat  = xc_t + DI * LL;                 // LL*DI
    float* xconv  = z_nat + DI * LL;                // DI*LL
    float* xs1    = xconv + DI * LL;                // DI*LL
    float* Bn     = xs1 + DI * LL;                  // KK*LL*NS
    float* Cn     = Bn + (size_t)KK * LL * NS;      // KK*LL*NS
    float* delta  = Cn + (size_t)KK * LL * NS;      // KK*DI*LL
    float* ybuf   = delta + (size_t)KK * DI * LL;   // KK*DI*LL (own-frame positions)
    float* ym     = xc_t;                           // alias: DI*LL (merged natural)

    k_inproj <<<dim3(LL / 64, 12), 256, 0, stream>>>(x, ipw, xc_t, z_nat);
    k_convT  <<<dim3(DI, 4), 256, 0, stream>>>(xc_t, cw, cb, xconv, xs1);
    k_xdblD  <<<dim3(LL / 32, KK), 256, 0, stream>>>(xconv, xs1, xpw, dtw, dtb, Bn, Cn, delta);
    k_scan   <<<KK * DI, 1024, 0, stream>>>(delta, Bn, Cn, xconv, xs1, alog, Dsp, ybuf);
    k_merge4 <<<DI, 256, 0, stream>>>(ybuf, ym);
    k_lnout  <<<LL / 32, 256, 0, stream>>>(ym, z_nat, lnw, lnb, ow, out);
}

// Round 8
// 204.972 us; speedup vs baseline: 1.0538x; 1.0538x over previous
//
#include <hip/hip_runtime.h>
#include <hip/hip_bf16.h>
#include <math.h>

// SS2D (VMamba) forward, MI355X. Constants from the reference.
#define DM 96
#define DI 192
#define NS 16            // state dim N
#define KK 4             // directions
#define RR 6             // dt rank
#define HH 56
#define WW 56
#define LL (HH*WW)       // 3136
#define RN (RR + 2*NS)   // 38 rows of x_dbl
#define NCH 64           // scan chunks per sequence
#define CLL (LL/NCH)     // 49 steps per chunk

__device__ __forceinline__ float silu_f(float x) { return x / (1.f + __expf(-x)); }
__device__ __forceinline__ float softplus_f(float x) {
    return (x > 20.f) ? x : log1pf(__expf(x));
}

// K1: tiled GEMM xz[o][l]; o<DI -> xc_t[o][l]; o>=DI -> silu -> z_nat[l][o-DI]
__global__ __launch_bounds__(256) void k_inproj(
        const float* __restrict__ x, const float* __restrict__ w,
        float* __restrict__ xc_t, float* __restrict__ z_nat) {
    __shared__ float xt[64 * 100];
    __shared__ float wt[32 * 100];
    const int l0 = blockIdx.x * 64;
    const int o0 = blockIdx.y * 32;
    const int tid = threadIdx.x;
    for (int i = tid; i < 64 * 96; i += 256) {
        int r = i / 96, c = i % 96;
        xt[r * 100 + c] = x[(size_t)(l0 + r) * DM + c];
    }
    for (int i = tid; i < 32 * 96; i += 256) {
        int r = i / 96, c = i % 96;
        wt[r * 100 + c] = w[(size_t)(o0 + r) * DM + c];
    }
    __syncthreads();
    const int tx = tid & 15, ty = tid >> 4;        // tx: o, ty: l
    float acc[4][2] = {};
    for (int c = 0; c < 96; c += 4) {
        float4 av[4], bv[2];
#pragma unroll
        for (int i = 0; i < 4; ++i) av[i] = *(const float4*)&xt[(ty + 16 * i) * 100 + c];
#pragma unroll
        for (int j = 0; j < 2; ++j) bv[j] = *(const float4*)&wt[(tx + 16 * j) * 100 + c];
#pragma unroll
        for (int i = 0; i < 4; ++i)
#pragma unroll
            for (int j = 0; j < 2; ++j) {
                acc[i][j] = fmaf(av[i].x, bv[j].x, acc[i][j]);
                acc[i][j] = fmaf(av[i].y, bv[j].y, acc[i][j]);
                acc[i][j] = fmaf(av[i].z, bv[j].z, acc[i][j]);
                acc[i][j] = fmaf(av[i].w, bv[j].w, acc[i][j]);
            }
    }
    __syncthreads();
    float* ot = xt;                                // reuse as [o][l] 32x65
#pragma unroll
    for (int j = 0; j < 2; ++j)
#pragma unroll
        for (int i = 0; i < 4; ++i)
            ot[(tx + 16 * j) * 65 + (ty + 16 * i)] = acc[i][j];
    __syncthreads();
    if (o0 < DI) {
        for (int i = tid; i < 32 * 64; i += 256) {
            int ol = i >> 6, ll = i & 63;
            xc_t[(size_t)(o0 + ol) * LL + l0 + ll] = ot[ol * 65 + ll];
        }
    } else {
        for (int i = tid; i < 32 * 64; i += 256) {
            int ll = i >> 5, ol = i & 31;
            z_nat[(size_t)(l0 + ll) * DI + (o0 - DI) + ol] = silu_f(ot[ol * 65 + ll]);
        }
    }
}

// K2: depthwise 3x3 conv SAME + bias + silu + spatial transpose, band-split.
__global__ __launch_bounds__(256) void k_convT(
        const float* __restrict__ xc_t, const float* __restrict__ cw,
        const float* __restrict__ cb, float* __restrict__ xconv, float* __restrict__ xs1) {
    __shared__ float in_s[16 * 56];
    __shared__ float out_s[14 * 57];
    const int d = blockIdx.x;
    const int h0 = blockIdx.y * 14;
    const int tid = threadIdx.x;
    const float* in = xc_t + (size_t)d * LL;
    for (int i = tid; i < 16 * 56; i += 256) {
        int r = i / 56 - 1 + h0;
        int cpos = i % 56;
        in_s[i] = (r >= 0 && r < HH) ? in[r * WW + cpos] : 0.f;
    }
    __syncthreads();
    const float b0 = cb[d];
    float w9[9];
#pragma unroll
    for (int i = 0; i < 9; ++i) w9[i] = cw[d * 9 + i];
    for (int i = tid; i < 14 * 56; i += 256) {
        int hh = i / 56, w = i % 56;
        float acc = b0;
#pragma unroll
        for (int di = 0; di < 3; ++di)
#pragma unroll
            for (int dj = 0; dj < 3; ++dj) {
                int w2 = w + dj - 1;
                if (w2 < 0 || w2 >= WW) continue;
                acc = fmaf(in_s[(hh + di) * 56 + w2], w9[di * 3 + dj], acc);
            }
        acc = silu_f(acc);
        xconv[(size_t)d * LL + (h0 + hh) * WW + w] = acc;
        out_s[hh * 57 + w] = acc;
    }
    __syncthreads();
    for (int i = tid; i < 14 * 56; i += 256) {
        int w = i / 14, hh = i % 14;
        xs1[(size_t)d * LL + w * HH + h0 + hh] = out_s[hh * 57 + w];
    }
}

// K3: x_dbl + delta fused, l-tile 32. Both operands LDS-staged. Grid (98, 4).
__global__ __launch_bounds__(256) void k_xdblD(
        const float* __restrict__ xconv, const float* __restrict__ xs1,
        const float* __restrict__ pw, const float* __restrict__ dtw,
        const float* __restrict__ dtb,
        float* __restrict__ Bn, float* __restrict__ Cn, float* __restrict__ delta) {
    __shared__ float xt[DI * 32];                  // [d][sx]
    __shared__ float wk_s[32 * DI];                // [col][d]
    __shared__ float dtS[RR * 33];
    const int k = blockIdx.y;
    const int l0 = blockIdx.x * 32;
    const int tid = threadIdx.x;
    const float* in = (k & 1) ? xs1 : xconv;
    const float* wk = pw + (size_t)k * RN * DI;
    for (int i = tid; i < DI * 32; i += 256) {
        int d = i >> 5, lx = i & 31;
        xt[i] = in[(size_t)d * LL + l0 + lx];
    }
    {
        const float4* src = (const float4*)(wk + RR * DI);
        float4* dst = (float4*)wk_s;
        for (int i = tid; i < (32 * DI) / 4; i += 256) dst[i] = src[i];
    }
    __syncthreads();
    if (tid < RR * 32) {
        int r = tid >> 5, lx = tid & 31;
        const float* wr = wk + r * DI;
        float acc = 0.f;
#pragma unroll 8
        for (int d = 0; d < DI; ++d) acc = fmaf(xt[(d << 5) + lx], wr[d], acc);
        dtS[r * 33 + lx] = acc;
    }
    {
        const int sx = tid & 31, cg = tid >> 5;
        float acc4[4] = {};
        for (int d = 0; d < DI; d += 4) {
            float x0 = xt[(d + 0) * 32 + sx];
            float x1 = xt[(d + 1) * 32 + sx];
            float x2 = xt[(d + 2) * 32 + sx];
            float x3 = xt[(d + 3) * 32 + sx];
#pragma unroll
            for (int j = 0; j < 4; ++j) {
                float4 wv = *(const float4*)&wk_s[(cg + 8 * j) * DI + d];
                acc4[j] = fmaf(x0, wv.x, acc4[j]);
                acc4[j] = fmaf(x1, wv.y, acc4[j]);
                acc4[j] = fmaf(x2, wv.z, acc4[j]);
                acc4[j] = fmaf(x3, wv.w, acc4[j]);
            }
        }
        int s = l0 + sx;
#pragma unroll
        for (int j = 0; j < 4; ++j) {
            int col = cg + 8 * j;
            if (col < NS) Bn[((size_t)k * LL + s) * NS + col] = acc4[j];
            else          Cn[((size_t)k * LL + s) * NS + (col - NS)] = acc4[j];
        }
    }
    __syncthreads();
    for (int oi = tid; oi < DI * 32; oi += 256) {
        int d = oi >> 5, sl = oi & 31;
        int kd = k * DI + d;
        const float* wr = dtw + (size_t)kd * RR;
        float acc = dtb[kd];
#pragma unroll
        for (int r = 0; r < RR; ++r) acc = fmaf(dtS[r * 33 + sl], wr[r], acc);
        delta[(size_t)kd * LL + l0 + sl] = softplus_f(acc);
    }
}

// ---- templated scan body: STP = +1 (k=0,1) or -1 (k=2,3), literal strides ----
template<int STP>
__device__ __forceinline__ void scan_dir(
        const float* __restrict__ pd, const float* __restrict__ pu,
        const float* __restrict__ pB, const float* __restrict__ pC,
        float An, float Dv, int c, int n,
        float* __restrict__ sP, float* __restrict__ sH,
        float* __restrict__ yo0 /* direction-adjusted base */) {
    // Phase 1: chunk-local scan (h=0 start); P = exp(An * sum(dl))
    float sd = 0.f, h = 0.f;
#pragma unroll 7
    for (int tl = 0; tl < CLL; ++tl) {
        float dl = pd[STP * tl];
        float u  = pu[STP * tl];
        float Bv = pB[STP * NS * tl];
        float dA = __expf(dl * An);
        h = fmaf(dA, h, dl * Bv * u);
        sd += dl;
    }
    sP[c * NS + n] = __expf(sd * An);
    sH[c * NS + n] = h;
    __syncthreads();
    float hin = 0.f;
    for (int cc = 0; cc < c; ++cc)
        hin = fmaf(sP[cc * NS + n], hin, sH[cc * NS + n]);

    // Phase 2: rescan with carry, emit y (register-batched coalesced stores)
    float h2 = hin;
    float yreg[4];
#pragma unroll 7
    for (int tl = 0; tl < CLL; ++tl) {
        float dl = pd[STP * tl];
        float u  = pu[STP * tl];
        float Bv = pB[STP * NS * tl];
        float Cv = pC[STP * NS * tl];
        float dA = __expf(dl * An);
        h2 = fmaf(dA, h2, dl * Bv * u);
        float acc = h2 * Cv;
        acc += __shfl_xor(acc, 8, 64);
        acc += __shfl_xor(acc, 4, 64);
        acc += __shfl_xor(acc, 2, 64);
        acc += __shfl_xor(acc, 1, 64);
        acc = fmaf(Dv, u, acc);
        if ((tl & 15) == n) yreg[tl >> 4] = acc;
    }
#pragma unroll
    for (int j = 0; j < 3; ++j)
        yo0[STP * (j * 16 + n)] = yreg[j];
    if (n == 0)
        yo0[STP * 48] = yreg[3];
}

// K4: chunked selective scan, 64 chunks x 49 steps, one (k,d) per 1024-thread block.
// Direction is a compile-time template -> all step offsets fold into load immediates.
__global__ __launch_bounds__(1024) void k_scan(
        const float* __restrict__ delta, const float* __restrict__ Bn,
        const float* __restrict__ Cn,
        const float* __restrict__ xconv, const float* __restrict__ xs1,
        const float* __restrict__ A_logs, const float* __restrict__ Ds,
        float* __restrict__ ybuf) {
    __shared__ float sP[NCH * NS];
    __shared__ float sH[NCH * NS];
    int b = blockIdx.x;
    int k = b / DI, d = b % DI;
    int tid = threadIdx.x;
    int c = tid >> 4, n = tid & 15;
    int kd = k * DI + d;
    float An = -__expf(A_logs[kd * NS + n]);
    float Dv = Ds[kd];
    const float* del = delta + (size_t)kd * LL;
    const float* uP  = ((k & 1) ? xs1 : xconv) + (size_t)d * LL;
    const float* Bb  = Bn + (size_t)k * LL * NS;
    const float* Cb  = Cn + (size_t)k * LL * NS;
    float* yo = ybuf + (size_t)kd * LL;
    const int t0 = c * CLL;
    if (k < 2) {
        const int im0 = t0;
        scan_dir<1>(del + im0, uP + im0,
                    Bb + (size_t)im0 * NS + n, Cb + (size_t)im0 * NS + n,
                    An, Dv, c, n, sP, sH, yo + t0);
    } else {
        const int im0 = LL - 1 - t0;
        scan_dir<-1>(del + im0, uP + im0,
                     Bb + (size_t)im0 * NS + n, Cb + (size_t)im0 * NS + n,
                     An, Dv, c, n, sP, sH, yo + im0);
    }
}

// K5: merge 4 directions -> ym[d][p] (natural space). One block per channel d.
__global__ __launch_bounds__(256) void k_merge4(
        const float* __restrict__ ybuf, float* __restrict__ ym) {
    __shared__ float ts[HH * 57];
    const int d = blockIdx.x;
    const int tid = threadIdx.x;
    const float* r1 = ybuf + (size_t)(DI + d) * LL;
    const float* r3 = ybuf + (size_t)(3 * DI + d) * LL;
    for (int s = tid; s < LL; s += 256) {
        int w = s / HH, h = s % HH;
        ts[h * 57 + w] = r1[s] + r3[s];
    }
    __syncthreads();
    const float* r0 = ybuf + (size_t)d * LL;
    const float* r2 = ybuf + (size_t)(2 * DI + d) * LL;
    float* yo = ym + (size_t)d * LL;
    for (int p = tid; p < LL; p += 256) {
        int h = p / WW, w = p % WW;
        yo[p] = r0[p] + r2[p] + ts[h * 57 + w];
    }
}

// K6: LayerNorm + gate(z) + out-proj. 32 l per block, grid 98.
__global__ __launch_bounds__(256) void k_lnout(
        const float* __restrict__ ym, const float* __restrict__ z_nat,
        const float* __restrict__ lnw, const float* __restrict__ lnb,
        const float* __restrict__ ow, float* __restrict__ out) {
    __shared__ float yv[32 * 196];
    __shared__ float ow_s[48 * 196];
    __shared__ float mean_s[32], inv_s[32];
    const int l0 = blockIdx.x * 32;
    const int tid = threadIdx.x;
    for (int i = tid; i < DI * 32; i += 256) {
        int d = i >> 5, p = i & 31;
        yv[p * 196 + d] = ym[(size_t)d * LL + l0 + p];
    }
    __syncthreads();
    {
        int p = tid >> 3, e = tid & 7;
        float s1 = 0.f;
#pragma unroll
        for (int m = 0; m < 24; ++m) s1 += yv[p * 196 + e + 8 * m];
        s1 += __shfl_xor(s1, 4, 64);
        s1 += __shfl_xor(s1, 2, 64);
        s1 += __shfl_xor(s1, 1, 64);
        float mean = s1 * (1.f / DI);
        float s2 = 0.f;
#pragma unroll
        for (int m = 0; m < 24; ++m) {
            float dv = yv[p * 196 + e + 8 * m] - mean;
            s2 = fmaf(dv, dv, s2);
        }
        s2 += __shfl_xor(s2, 4, 64);
        s2 += __shfl_xor(s2, 2, 64);
        s2 += __shfl_xor(s2, 1, 64);
        if (e == 0) {
            mean_s[p] = mean;
            inv_s[p] = rsqrtf(s2 * (1.f / DI) + 1e-5f);
        }
    }
    __syncthreads();
    for (int i = tid; i < DI * 32; i += 256) {
        int p = i / DI, d = i % DI;
        float yn = (yv[p * 196 + d] - mean_s[p]) * inv_s[p] * lnw[d] + lnb[d];
        yv[p * 196 + d] = yn * z_nat[(size_t)(l0 + p) * DI + d];
    }
    __syncthreads();
    const int ty = tid >> 4, tx = tid & 15;        // ty: l-pair, tx: o
#pragma unroll
    for (int pass = 0; pass < 2; ++pass) {
        for (int i = tid; i < 48 * DI; i += 256) {
            int o = i / DI, dd = i % DI;
            ow_s[o * 196 + dd] = ow[(size_t)(pass * 48 + o) * DI + dd];
        }
        __syncthreads();
        float acc[2][3] = {};
        for (int dd = 0; dd < DI; dd += 4) {
            float4 a0 = *(const float4*)&yv[(ty * 2 + 0) * 196 + dd];
            float4 a1 = *(const float4*)&yv[(ty * 2 + 1) * 196 + dd];
#pragma unroll
            for (int j = 0; j < 3; ++j) {
                float4 bv = *(const float4*)&ow_s[(tx + 16 * j) * 196 + dd];
                acc[0][j] += a0.x * bv.x + a0.y * bv.y + a0.z * bv.z + a0.w * bv.w;
                acc[1][j] += a1.x * bv.x + a1.y * bv.y + a1.z * bv.z + a1.w * bv.w;
            }
        }
#pragma unroll
        for (int il = 0; il < 2; ++il)
#pragma unroll
            for (int j = 0; j < 3; ++j)
                out[(size_t)(l0 + ty * 2 + il) * DM + pass * 48 + tx + 16 * j] = acc[il][j];
        __syncthreads();
    }
}

extern "C" void kernel_launch(void* const* d_in, const int* in_sizes, int n_in,
                              void* d_out, int out_size, void* d_ws, size_t ws_size,
                              hipStream_t stream) {
    const float* x    = (const float*)d_in[0];
    const float* ipw  = (const float*)d_in[1];
    const float* cw   = (const float*)d_in[2];
    const float* cb   = (const float*)d_in[3];
    const float* xpw  = (const float*)d_in[4];
    const float* dtw  = (const float*)d_in[5];
    const float* dtb  = (const float*)d_in[6];
    const float* alog = (const float*)d_in[7];
    const float* Dsp  = (const float*)d_in[8];
    const float* lnw  = (const float*)d_in[9];
    const float* lnb  = (const float*)d_in[10];
    const float* ow   = (const float*)d_in[11];
    float* out = (float*)d_out;

    float* ws     = (float*)d_ws;
    float* xc_t   = ws;                             // DI*LL (dead after convT)
    float* z_nat  = xc_t + DI * LL;                 // LL*DI
    float* xconv  = z_nat + DI * LL;                // DI*LL
    float* xs1    = xconv + DI * LL;                // DI*LL
    float* Bn     = xs1 + DI * LL;                  // KK*LL*NS
    float* Cn     = Bn + (size_t)KK * LL * NS;      // KK*LL*NS
    float* delta  = Cn + (size_t)KK * LL * NS;      // KK*DI*LL
    float* ybuf   = delta + (size_t)KK * DI * LL;   // KK*DI*LL (own-frame positions)
    float* ym     = xc_t;                           // alias: DI*LL (merged natural)

    k_inproj <<<dim3(LL / 64, 12), 256, 0, stream>>>(x, ipw, xc_t, z_nat);
    k_convT  <<<dim3(DI, 4), 256, 0, stream>>>(xc_t, cw, cb, xconv, xs1);
    k_xdblD  <<<dim3(LL / 32, KK), 256, 0, stream>>>(xconv, xs1, xpw, dtw, dtb, Bn, Cn, delta);
    k_scan   <<<KK * DI, 1024, 0, stream>>>(delta, Bn, Cn, xconv, xs1, alog, Dsp, ybuf);
    k_merge4 <<<DI, 256, 0, stream>>>(ybuf, ym);
    k_lnout  <<<LL / 32, 256, 0, stream>>>(ym, z_nat, lnw, lnb, ow, out);
}

// Round 9
// 187.748 us; speedup vs baseline: 1.1505x; 1.0917x over previous
//
#include <hip/hip_runtime.h>
#include <hip/hip_bf16.h>
#include <math.h>

// SS2D (VMamba) forward, MI355X. Constants from the reference.
#define DM 96
#define DI 192
#define NS 16            // state dim N
#define KK 4             // directions
#define RR 6             // dt rank
#define HH 56
#define WW 56
#define LL (HH*WW)       // 3136
#define RN (RR + 2*NS)   // 38 rows of x_dbl
#define NCH 64           // scan chunks per sequence
#define CLL (LL/NCH)     // 49 steps per chunk

__device__ __forceinline__ float silu_f(float x) { return x / (1.f + __expf(-x)); }
__device__ __forceinline__ float softplus_f(float x) {
    return (x > 20.f) ? x : log1pf(__expf(x));
}

// K1: tiled GEMM xz[o][l]; o<DI -> xc_t[o][l]; o>=DI -> silu -> z_nat[l][o-DI]
__global__ __launch_bounds__(256) void k_inproj(
        const float* __restrict__ x, const float* __restrict__ w,
        float* __restrict__ xc_t, float* __restrict__ z_nat) {
    __shared__ float xt[64 * 100];
    __shared__ float wt[32 * 100];
    const int l0 = blockIdx.x * 64;
    const int o0 = blockIdx.y * 32;
    const int tid = threadIdx.x;
    for (int i = tid; i < 64 * 96; i += 256) {
        int r = i / 96, c = i % 96;
        xt[r * 100 + c] = x[(size_t)(l0 + r) * DM + c];
    }
    for (int i = tid; i < 32 * 96; i += 256) {
        int r = i / 96, c = i % 96;
        wt[r * 100 + c] = w[(size_t)(o0 + r) * DM + c];
    }
    __syncthreads();
    const int tx = tid & 15, ty = tid >> 4;        // tx: o, ty: l
    float acc[4][2] = {};
    for (int c = 0; c < 96; c += 4) {
        float4 av[4], bv[2];
#pragma unroll
        for (int i = 0; i < 4; ++i) av[i] = *(const float4*)&xt[(ty + 16 * i) * 100 + c];
#pragma unroll
        for (int j = 0; j < 2; ++j) bv[j] = *(const float4*)&wt[(tx + 16 * j) * 100 + c];
#pragma unroll
        for (int i = 0; i < 4; ++i)
#pragma unroll
            for (int j = 0; j < 2; ++j) {
                acc[i][j] = fmaf(av[i].x, bv[j].x, acc[i][j]);
                acc[i][j] = fmaf(av[i].y, bv[j].y, acc[i][j]);
                acc[i][j] = fmaf(av[i].z, bv[j].z, acc[i][j]);
                acc[i][j] = fmaf(av[i].w, bv[j].w, acc[i][j]);
            }
    }
    __syncthreads();
    float* ot = xt;                                // reuse as [o][l] 32x65
#pragma unroll
    for (int j = 0; j < 2; ++j)
#pragma unroll
        for (int i = 0; i < 4; ++i)
            ot[(tx + 16 * j) * 65 + (ty + 16 * i)] = acc[i][j];
    __syncthreads();
    if (o0 < DI) {
        for (int i = tid; i < 32 * 64; i += 256) {
            int ol = i >> 6, ll = i & 63;
            xc_t[(size_t)(o0 + ol) * LL + l0 + ll] = ot[ol * 65 + ll];
        }
    } else {
        for (int i = tid; i < 32 * 64; i += 256) {
            int ll = i >> 5, ol = i & 31;
            z_nat[(size_t)(l0 + ll) * DI + (o0 - DI) + ol] = silu_f(ot[ol * 65 + ll]);
        }
    }
}

// K2: depthwise 3x3 conv SAME + bias + silu + spatial transpose, band-split.
__global__ __launch_bounds__(256) void k_convT(
        const float* __restrict__ xc_t, const float* __restrict__ cw,
        const float* __restrict__ cb, float* __restrict__ xconv, float* __restrict__ xs1) {
    __shared__ float in_s[16 * 56];
    __shared__ float out_s[14 * 57];
    const int d = blockIdx.x;
    const int h0 = blockIdx.y * 14;
    const int tid = threadIdx.x;
    const float* in = xc_t + (size_t)d * LL;
    for (int i = tid; i < 16 * 56; i += 256) {
        int r = i / 56 - 1 + h0;
        int cpos = i % 56;
        in_s[i] = (r >= 0 && r < HH) ? in[r * WW + cpos] : 0.f;
    }
    __syncthreads();
    const float b0 = cb[d];
    float w9[9];
#pragma unroll
    for (int i = 0; i < 9; ++i) w9[i] = cw[d * 9 + i];
    for (int i = tid; i < 14 * 56; i += 256) {
        int hh = i / 56, w = i % 56;
        float acc = b0;
#pragma unroll
        for (int di = 0; di < 3; ++di)
#pragma unroll
            for (int dj = 0; dj < 3; ++dj) {
                int w2 = w + dj - 1;
                if (w2 < 0 || w2 >= WW) continue;
                acc = fmaf(in_s[(hh + di) * 56 + w2], w9[di * 3 + dj], acc);
            }
        acc = silu_f(acc);
        xconv[(size_t)d * LL + (h0 + hh) * WW + w] = acc;
        out_s[hh * 57 + w] = acc;
    }
    __syncthreads();
    for (int i = tid; i < 14 * 56; i += 256) {
        int w = i / 14, hh = i % 14;
        xs1[(size_t)d * LL + w * HH + h0 + hh] = out_s[hh * 57 + w];
    }
}

// K3: x_dbl + delta fused, l-tile 32. Both operands LDS-staged. Grid (98, 4).
__global__ __launch_bounds__(256) void k_xdblD(
        const float* __restrict__ xconv, const float* __restrict__ xs1,
        const float* __restrict__ pw, const float* __restrict__ dtw,
        const float* __restrict__ dtb,
        float* __restrict__ Bn, float* __restrict__ Cn, float* __restrict__ delta) {
    __shared__ float xt[DI * 32];                  // [d][sx]
    __shared__ float wk_s[32 * DI];                // [col][d]
    __shared__ float dtS[RR * 33];
    const int k = blockIdx.y;
    const int l0 = blockIdx.x * 32;
    const int tid = threadIdx.x;
    const float* in = (k & 1) ? xs1 : xconv;
    const float* wk = pw + (size_t)k * RN * DI;
    for (int i = tid; i < DI * 32; i += 256) {
        int d = i >> 5, lx = i & 31;
        xt[i] = in[(size_t)d * LL + l0 + lx];
    }
    {
        const float4* src = (const float4*)(wk + RR * DI);
        float4* dst = (float4*)wk_s;
        for (int i = tid; i < (32 * DI) / 4; i += 256) dst[i] = src[i];
    }
    __syncthreads();
    if (tid < RR * 32) {
        int r = tid >> 5, lx = tid & 31;
        const float* wr = wk + r * DI;
        float acc = 0.f;
#pragma unroll 8
        for (int d = 0; d < DI; ++d) acc = fmaf(xt[(d << 5) + lx], wr[d], acc);
        dtS[r * 33 + lx] = acc;
    }
    {
        const int sx = tid & 31, cg = tid >> 5;
        float acc4[4] = {};
        for (int d = 0; d < DI; d += 4) {
            float x0 = xt[(d + 0) * 32 + sx];
            float x1 = xt[(d + 1) * 32 + sx];
            float x2 = xt[(d + 2) * 32 + sx];
            float x3 = xt[(d + 3) * 32 + sx];
#pragma unroll
            for (int j = 0; j < 4; ++j) {
                float4 wv = *(const float4*)&wk_s[(cg + 8 * j) * DI + d];
                acc4[j] = fmaf(x0, wv.x, acc4[j]);
                acc4[j] = fmaf(x1, wv.y, acc4[j]);
                acc4[j] = fmaf(x2, wv.z, acc4[j]);
                acc4[j] = fmaf(x3, wv.w, acc4[j]);
            }
        }
        int s = l0 + sx;
#pragma unroll
        for (int j = 0; j < 4; ++j) {
            int col = cg + 8 * j;
            if (col < NS) Bn[((size_t)k * LL + s) * NS + col] = acc4[j];
            else          Cn[((size_t)k * LL + s) * NS + (col - NS)] = acc4[j];
        }
    }
    __syncthreads();
    for (int oi = tid; oi < DI * 32; oi += 256) {
        int d = oi >> 5, sl = oi & 31;
        int kd = k * DI + d;
        const float* wr = dtw + (size_t)kd * RR;
        float acc = dtb[kd];
#pragma unroll
        for (int r = 0; r < RR; ++r) acc = fmaf(dtS[r * 33 + sl], wr[r], acc);
        delta[(size_t)kd * LL + l0 + sl] = softplus_f(acc);
    }
}

// ---- templated scan body: STP = +/-1 literal strides; TRANS routes the output
// through a padded LDS tile so k-odd directions land in NATURAL space. ----
template<int STP, bool TRANS>
__device__ __forceinline__ void scan_dir(
        const float* __restrict__ pd, const float* __restrict__ pu,
        const float* __restrict__ pB, const float* __restrict__ pC,
        float An, float Dv, int c, int n,
        float* __restrict__ sP, float* __restrict__ sH,
        float* __restrict__ yo0,   // !TRANS: direction-adjusted global base
        float* __restrict__ ysm,   // TRANS: LDS tile [HH][57]
        int im0) {
    // Phase 1: chunk-local scan (h=0 start); P = exp(An * sum(dl))
    float sd = 0.f, h = 0.f;
#pragma unroll 7
    for (int tl = 0; tl < CLL; ++tl) {
        float dl = pd[STP * tl];
        float u  = pu[STP * tl];
        float Bv = pB[STP * NS * tl];
        float dA = __expf(dl * An);
        h = fmaf(dA, h, dl * Bv * u);
        sd += dl;
    }
    sP[c * NS + n] = __expf(sd * An);
    sH[c * NS + n] = h;
    __syncthreads();
    float hin = 0.f;
    for (int cc = 0; cc < c; ++cc)
        hin = fmaf(sP[cc * NS + n], hin, sH[cc * NS + n]);

    // Phase 2: rescan with carry, emit y
    float h2 = hin;
    float yreg[4];
#pragma unroll 7
    for (int tl = 0; tl < CLL; ++tl) {
        float dl = pd[STP * tl];
        float u  = pu[STP * tl];
        float Bv = pB[STP * NS * tl];
        float Cv = pC[STP * NS * tl];
        float dA = __expf(dl * An);
        h2 = fmaf(dA, h2, dl * Bv * u);
        float acc = h2 * Cv;
        acc += __shfl_xor(acc, 8, 64);
        acc += __shfl_xor(acc, 4, 64);
        acc += __shfl_xor(acc, 2, 64);
        acc += __shfl_xor(acc, 1, 64);
        acc = fmaf(Dv, u, acc);
        if ((tl & 15) == n) yreg[tl >> 4] = acc;
    }
    if (!TRANS) {
#pragma unroll
        for (int j = 0; j < 3; ++j)
            yo0[STP * (j * 16 + n)] = yreg[j];
        if (n == 0)
            yo0[STP * 48] = yreg[3];
    } else {
        // im = index in transposed frame (s = w*HH + h); natural tile slot [h][w]
#pragma unroll
        for (int j = 0; j < 3; ++j) {
            int im = im0 + STP * (j * 16 + n);
            int w = im / HH, hh = im - w * HH;
            ysm[hh * 57 + w] = yreg[j];
        }
        if (n == 0) {
            int im = im0 + STP * 48;
            int w = im / HH, hh = im - w * HH;
            ysm[hh * 57 + w] = yreg[3];
        }
    }
}

// K4: chunked selective scan; all 4 directions written to y4[kd][p] in NATURAL space.
__global__ __launch_bounds__(1024) void k_scan(
        const float* __restrict__ delta, const float* __restrict__ Bn,
        const float* __restrict__ Cn,
        const float* __restrict__ xconv, const float* __restrict__ xs1,
        const float* __restrict__ A_logs, const float* __restrict__ Ds,
        float* __restrict__ y4) {
    __shared__ float sP[NCH * NS];
    __shared__ float sH[NCH * NS];
    __shared__ float ys[HH * 57];                  // 12.8 KB, k-odd transpose tile
    int b = blockIdx.x;
    int k = b / DI, d = b % DI;
    int tid = threadIdx.x;
    int c = tid >> 4, n = tid & 15;
    int kd = k * DI + d;
    float An = -__expf(A_logs[kd * NS + n]);
    float Dv = Ds[kd];
    const float* del = delta + (size_t)kd * LL;
    const float* uP  = ((k & 1) ? xs1 : xconv) + (size_t)d * LL;
    const float* Bb  = Bn + (size_t)k * LL * NS;
    const float* Cb  = Cn + (size_t)k * LL * NS;
    float* yo = y4 + (size_t)kd * LL;
    const int t0 = c * CLL;
    const int imF = t0;                  // forward base
    const int imR = LL - 1 - t0;         // reverse base
    if (k == 0) {
        scan_dir<1, false>(del + imF, uP + imF,
                           Bb + (size_t)imF * NS + n, Cb + (size_t)imF * NS + n,
                           An, Dv, c, n, sP, sH, yo + imF, nullptr, 0);
    } else if (k == 1) {
        scan_dir<1, true>(del + imF, uP + imF,
                          Bb + (size_t)imF * NS + n, Cb + (size_t)imF * NS + n,
                          An, Dv, c, n, sP, sH, nullptr, ys, imF);
    } else if (k == 2) {
        scan_dir<-1, false>(del + imR, uP + imR,
                            Bb + (size_t)imR * NS + n, Cb + (size_t)imR * NS + n,
                            An, Dv, c, n, sP, sH, yo + imR, nullptr, 0);
    } else {
        scan_dir<-1, true>(del + imR, uP + imR,
                           Bb + (size_t)imR * NS + n, Cb + (size_t)imR * NS + n,
                           An, Dv, c, n, sP, sH, nullptr, ys, imR);
    }
    if (k & 1) {                         // block-uniform branch
        __syncthreads();
        for (int p = tid; p < LL; p += 1024)
            yo[p] = ys[p + p / WW];      // [h][w] tile, stride 57: idx = p + p/56
    }
}

// K5: merge 4 natural rows + LayerNorm + gate(z) + out-proj (one 48-o pass).
// Grid (98, 2): blockIdx.y picks the ow half.
__global__ __launch_bounds__(256) void k_lnout(
        const float* __restrict__ y4, const float* __restrict__ z_nat,
        const float* __restrict__ lnw, const float* __restrict__ lnb,
        const float* __restrict__ ow, float* __restrict__ out) {
    __shared__ float yv[32 * 196];
    __shared__ float ow_s[48 * 196];
    __shared__ float mean_s[32], inv_s[32];
    const int l0 = blockIdx.x * 32;
    const int pass = blockIdx.y;
    const int tid = threadIdx.x;
    // merge 4 directions: coalesced 128B runs over p for each (k,d)
    for (int i = tid; i < DI * 32; i += 256) {
        int d = i >> 5, p = i & 31;
        size_t off = (size_t)d * LL + l0 + p;
        float v = y4[off]
                + y4[(size_t)DI * LL + off]
                + y4[(size_t)(2 * DI) * LL + off]
                + y4[(size_t)(3 * DI) * LL + off];
        yv[p * 196 + d] = v;
    }
    __syncthreads();
    // LN stats: 8 lanes per p
    {
        int p = tid >> 3, e = tid & 7;
        float s1 = 0.f;
#pragma unroll
        for (int m = 0; m < 24; ++m) s1 += yv[p * 196 + e + 8 * m];
        s1 += __shfl_xor(s1, 4, 64);
        s1 += __shfl_xor(s1, 2, 64);
        s1 += __shfl_xor(s1, 1, 64);
        float mean = s1 * (1.f / DI);
        float s2 = 0.f;
#pragma unroll
        for (int m = 0; m < 24; ++m) {
            float dv = yv[p * 196 + e + 8 * m] - mean;
            s2 = fmaf(dv, dv, s2);
        }
        s2 += __shfl_xor(s2, 4, 64);
        s2 += __shfl_xor(s2, 2, 64);
        s2 += __shfl_xor(s2, 1, 64);
        if (e == 0) {
            mean_s[p] = mean;
            inv_s[p] = rsqrtf(s2 * (1.f / DI) + 1e-5f);
        }
    }
    __syncthreads();
    // normalize + gate (d-fast mapping: coalesced z reads)
    for (int i = tid; i < DI * 32; i += 256) {
        int p = i / DI, d = i % DI;
        float yn = (yv[p * 196 + d] - mean_s[p]) * inv_s[p] * lnw[d] + lnb[d];
        yv[p * 196 + d] = yn * z_nat[(size_t)(l0 + p) * DI + d];
    }
    // stage this pass's 48 ow rows
    for (int i = tid; i < 48 * DI; i += 256) {
        int o = i / DI, dd = i % DI;
        ow_s[o * 196 + dd] = ow[(size_t)(pass * 48 + o) * DI + dd];
    }
    __syncthreads();
    const int ty = tid >> 4, tx = tid & 15;        // ty: l-pair, tx: o
    float acc[2][3] = {};
    for (int dd = 0; dd < DI; dd += 4) {
        float4 a0 = *(const float4*)&yv[(ty * 2 + 0) * 196 + dd];
        float4 a1 = *(const float4*)&yv[(ty * 2 + 1) * 196 + dd];
#pragma unroll
        for (int j = 0; j < 3; ++j) {
            float4 bv = *(const float4*)&ow_s[(tx + 16 * j) * 196 + dd];
            acc[0][j] += a0.x * bv.x + a0.y * bv.y + a0.z * bv.z + a0.w * bv.w;
            acc[1][j] += a1.x * bv.x + a1.y * bv.y + a1.z * bv.z + a1.w * bv.w;
        }
    }
#pragma unroll
    for (int il = 0; il < 2; ++il)
#pragma unroll
        for (int j = 0; j < 3; ++j)
            out[(size_t)(l0 + ty * 2 + il) * DM + pass * 48 + tx + 16 * j] = acc[il][j];
}

extern "C" void kernel_launch(void* const* d_in, const int* in_sizes, int n_in,
                              void* d_out, int out_size, void* d_ws, size_t ws_size,
                              hipStream_t stream) {
    const float* x    = (const float*)d_in[0];
    const float* ipw  = (const float*)d_in[1];
    const float* cw   = (const float*)d_in[2];
    const float* cb   = (const float*)d_in[3];
    const float* xpw  = (const float*)d_in[4];
    const float* dtw  = (const float*)d_in[5];
    const float* dtb  = (const float*)d_in[6];
    const float* alog = (const float*)d_in[7];
    const float* Dsp  = (const float*)d_in[8];
    const float* lnw  = (const float*)d_in[9];
    const float* lnb  = (const float*)d_in[10];
    const float* ow   = (const float*)d_in[11];
    float* out = (float*)d_out;

    float* ws     = (float*)d_ws;
    float* xc_t   = ws;                             // DI*LL (dead after convT)
    float* z_nat  = xc_t + DI * LL;                 // LL*DI
    float* xconv  = z_nat + DI * LL;                // DI*LL
    float* xs1    = xconv + DI * LL;                // DI*LL
    float* Bn     = xs1 + DI * LL;                  // KK*LL*NS
    float* Cn     = Bn + (size_t)KK * LL * NS;      // KK*LL*NS
    float* delta  = Cn + (size_t)KK * LL * NS;      // KK*DI*LL
    float* y4     = delta + (size_t)KK * DI * LL;   // KK*DI*LL (natural p)

    k_inproj <<<dim3(LL / 64, 12), 256, 0, stream>>>(x, ipw, xc_t, z_nat);
    k_convT  <<<dim3(DI, 4), 256, 0, stream>>>(xc_t, cw, cb, xconv, xs1);
    k_xdblD  <<<dim3(LL / 32, KK), 256, 0, stream>>>(xconv, xs1, xpw, dtw, dtb, Bn, Cn, delta);
    k_scan   <<<KK * DI, 1024, 0, stream>>>(delta, Bn, Cn, xconv, xs1, alog, Dsp, y4);
    k_lnout  <<<dim3(LL / 32, 2), 256, 0, stream>>>(y4, z_nat, lnw, lnb, ow, out);
}